// Round 1
// baseline (52.726 us; speedup 1.0000x reference)
//
#include <hip/hip_runtime.h>

#define WINDOW 48
#define RES 50
#define PRED 96
#define SEG 100
#define BATCH 2048
#define KTRUNC 12

// ws layout (floats):
//   M  [RES][WINDOW]   at offset 0      (2400)
//   Dk [16][RES]       at offset 2400   (800)
//   L  [BATCH][RES]    at offset 3200   (102400)

__global__ void k0_setup(const float* __restrict__ W_lin,
                         const float* __restrict__ W_in,
                         const float* __restrict__ d,
                         float* __restrict__ ws) {
    float* M  = ws;
    float* Dk = ws + 2400;
    int tid = threadIdx.x;
    // M[r][w] = sum_v W_in[r][v] * W_lin[v][w]
    for (int e = tid; e < RES * WINDOW; e += blockDim.x) {
        int r = e / WINDOW, w = e % WINDOW;
        float acc = 0.f;
        for (int v = 0; v < WINDOW; ++v)
            acc = fmaf(W_in[r * WINDOW + v], W_lin[v * WINDOW + w], acc);
        M[e] = acc;
    }
    if (tid < RES) {
        float dv = d[tid];
        float d2 = dv * dv;
        float d4 = d2 * d2;
        float d8 = d4 * d4;
        float d16 = d8 * d8;
        float d32 = d16 * d16;
        float d64 = d32 * d32;
        float D = d64 * d32 * d4;   // d^100
        float p = 1.f;
        for (int k = 0; k < 16; ++k) { Dk[k * RES + tid] = p; p *= D; }
    }
}

// One block per batch b. Stage x row (4800 f32 = 19.2KB) in LDS.
// Threads t<200: (r = t/4, p = t&3); each handles j in {p, p+4, ..., p+96},
// computing acc = sum_j d^(99-j) * dot48(x[b,j,:], M[r,:]).
__global__ __launch_bounds__(256) void k1_local(const float* __restrict__ x,
                                                const float* __restrict__ Mg,
                                                const float* __restrict__ d,
                                                float* __restrict__ L) {
    __shared__ float Xs[SEG * WINDOW];   // 4800 floats
    int b = blockIdx.x;
    const float4* xrow = (const float4*)(x + (size_t)b * (SEG * WINDOW));
    float4* Xs4 = (float4*)Xs;
    for (int i = threadIdx.x; i < (SEG * WINDOW) / 4; i += 256)
        Xs4[i] = xrow[i];
    __syncthreads();

    int t = threadIdx.x;
    if (t >= 4 * RES) return;
    int r = t >> 2, p = t & 3;

    float4 Mr[12];
    const float4* Mrow = (const float4*)(Mg + r * WINDOW);
#pragma unroll
    for (int q = 0; q < 12; ++q) Mr[q] = Mrow[q];

    float dv = d[r];
    float d2 = dv * dv, d4 = d2 * d2;
    float w = (p == 3) ? 1.f : (p == 2) ? dv : (p == 1) ? d2 : d2 * dv; // d^(3-p)

    float acc = 0.f;
    for (int s = 0; s < 25; ++s) {
        int j = p + 4 * (24 - s);          // descending j => ascending exponent
        const float4* xj = Xs4 + j * 12;
        float dot = 0.f;
#pragma unroll
        for (int q = 0; q < 12; ++q) {
            float4 xv = xj[q];
            dot = fmaf(xv.x, Mr[q].x, dot);
            dot = fmaf(xv.y, Mr[q].y, dot);
            dot = fmaf(xv.z, Mr[q].z, dot);
            dot = fmaf(xv.w, Mr[q].w, dot);
        }
        acc = fmaf(w, dot, acc);           // weight d^(99-j)
        w *= d4;
    }
    // reduce over the 4 phases (lanes r*4+p are contiguous, all active)
    acc += __shfl_xor(acc, 1);
    acc += __shfl_xor(acc, 2);
    if (p == 0) L[b * RES + r] = acc;
}

// One block per batch: s[r] = sum_k D^k * L[b-k][r]; out[b][o] = s . W_out[o]
__global__ __launch_bounds__(128) void k2_out(const float* __restrict__ L,
                                              const float* __restrict__ Dk,
                                              const float* __restrict__ W_out,
                                              float* __restrict__ out) {
    __shared__ float s_s[RES];
    int b = blockIdx.x;
    int t = threadIdx.x;
    if (t < RES) {
        float acc = 0.f;
#pragma unroll
        for (int k = 0; k < KTRUNC; ++k) {
            int bb = b - k;
            if (bb >= 0) acc = fmaf(Dk[k * RES + t], L[bb * RES + t], acc);
        }
        s_s[t] = acc;
    }
    __syncthreads();
    if (t < PRED) {
        const float* wrow = W_out + t * RES;
        float acc = 0.f;
#pragma unroll
        for (int r = 0; r < RES; ++r) acc = fmaf(s_s[r], wrow[r], acc);
        out[b * PRED + t] = acc;
    }
}

extern "C" void kernel_launch(void* const* d_in, const int* in_sizes, int n_in,
                              void* d_out, int out_size, void* d_ws, size_t ws_size,
                              hipStream_t stream) {
    const float* x     = (const float*)d_in[0];
    const float* W_lin = (const float*)d_in[1];
    const float* W_in  = (const float*)d_in[2];
    const float* d     = (const float*)d_in[3];
    const float* W_out = (const float*)d_in[4];
    float* out = (float*)d_out;
    float* ws  = (float*)d_ws;

    float* M  = ws;
    float* Dk = ws + 2400;
    float* L  = ws + 3200;

    k0_setup<<<1, 256, 0, stream>>>(W_lin, W_in, d, ws);
    k1_local<<<BATCH, 256, 0, stream>>>(x, M, d, L);
    k2_out<<<BATCH, 128, 0, stream>>>(L, Dk, W_out, out);
}

// Round 2
// 50.148 us; speedup vs baseline: 1.0514x; 1.0514x over previous
//
#include <hip/hip_runtime.h>

#define WINDOW 48
#define RES 50
#define PRED 96
#define SEG 100
#define BATCH 2048
#define KTRUNC 12
#define XPAD 52   // padded LDS row stride (floats)

// ws layout (floats):
//   M  [RES][WINDOW]   at offset 0      (2400)
//   Dk [16][RES]       at offset 2400   (800)
//   L  [BATCH][RES]    at offset 3200   (102400)

__global__ void k0_setup(const float* __restrict__ W_lin,
                         const float* __restrict__ W_in,
                         const float* __restrict__ d,
                         float* __restrict__ ws) {
    float* M  = ws;
    float* Dk = ws + 2400;
    int tid = threadIdx.x;
    // M[r][w] = sum_v W_in[r][v] * W_lin[v][w]
    for (int e = tid; e < RES * WINDOW; e += blockDim.x) {
        int r = e / WINDOW, w = e % WINDOW;
        float acc = 0.f;
        for (int v = 0; v < WINDOW; ++v)
            acc = fmaf(W_in[r * WINDOW + v], W_lin[v * WINDOW + w], acc);
        M[e] = acc;
    }
    if (tid < RES) {
        float dv = d[tid];
        float d2 = dv * dv;
        float d4 = d2 * d2;
        float d8 = d4 * d4;
        float d16 = d8 * d8;
        float d32 = d16 * d16;
        float d64 = d32 * d32;
        float D = d64 * d32 * d4;   // d^100
        float p = 1.f;
        for (int k = 0; k < 16; ++k) { Dk[k * RES + tid] = p; p *= D; }
    }
}

// One block per batch b. 250 active threads: (r = t%50, jg = t/50).
// Thread (r,jg): M[r,:] in 48 regs; loops j = jg*20+19 .. jg*20 reading the
// x row from LDS (broadcast across the 50 lanes sharing jg), accumulating
// acc = sum_j d^(99-j) * dot48(x[j,:], M[r,:]).  Then 5-way reduce over jg.
__global__ __launch_bounds__(256) void k1_local(const float* __restrict__ x,
                                                const float* __restrict__ Mg,
                                                const float* __restrict__ d,
                                                float* __restrict__ L) {
    __shared__ float Xs[SEG * XPAD];   // 5200 floats, padded rows
    __shared__ float Ms[RES * XPAD];   // 2600 floats, padded rows
    __shared__ float Ps[5 * RES];      // per-jg partials

    int b = blockIdx.x;
    const float4* xrow = (const float4*)(x + (size_t)b * (SEG * WINDOW));
    for (int e4 = threadIdx.x; e4 < SEG * 12; e4 += 256) {
        int j = e4 / 12, q = e4 % 12;
        *(float4*)(Xs + j * XPAD + 4 * q) = xrow[e4];
    }
    const float4* mrow = (const float4*)Mg;
    for (int e4 = threadIdx.x; e4 < RES * 12; e4 += 256) {
        int r = e4 / 12, q = e4 % 12;
        *(float4*)(Ms + r * XPAD + 4 * q) = mrow[e4];
    }
    __syncthreads();

    int t = threadIdx.x;
    if (t < 5 * RES) {
        int r = t % RES, jg = t / RES;

        float4 Mr[12];
#pragma unroll
        for (int q = 0; q < 12; ++q)
            Mr[q] = *(const float4*)(Ms + r * XPAD + 4 * q);

        float dv = d[r];
        float d2 = dv * dv, d4 = d2 * d2, d8 = d4 * d4, d16 = d8 * d8;
        float d20 = d16 * d4;
        // w starts at d^(99 - (jg*20+19)) = (d^20)^(4-jg)
        float w = 1.f;
        for (int k = jg; k < 4; ++k) w *= d20;

        float acc = 0.f;
        for (int i = 19; i >= 0; --i) {
            const float* xj = Xs + (jg * 20 + i) * XPAD;
            float dx = 0.f, dy = 0.f, dz = 0.f, dw = 0.f;  // 4 chains
#pragma unroll
            for (int q = 0; q < 12; ++q) {
                float4 xv = *(const float4*)(xj + 4 * q);
                dx = fmaf(xv.x, Mr[q].x, dx);
                dy = fmaf(xv.y, Mr[q].y, dy);
                dz = fmaf(xv.z, Mr[q].z, dz);
                dw = fmaf(xv.w, Mr[q].w, dw);
            }
            acc = fmaf(w, (dx + dy) + (dz + dw), acc);
            w *= dv;
        }
        Ps[jg * RES + r] = acc;
    }
    __syncthreads();
    if (t < RES) {
        float s = (Ps[t] + Ps[RES + t]) + (Ps[2 * RES + t] + Ps[3 * RES + t])
                  + Ps[4 * RES + t];
        L[b * RES + t] = s;
    }
}

// One block per batch: s[r] = sum_k D^k * L[b-k][r]; out[b][o] = s . W_out[o]
__global__ __launch_bounds__(128) void k2_out(const float* __restrict__ L,
                                              const float* __restrict__ Dk,
                                              const float* __restrict__ W_out,
                                              float* __restrict__ out) {
    __shared__ float s_s[RES];
    int b = blockIdx.x;
    int t = threadIdx.x;
    if (t < RES) {
        float acc = 0.f;
#pragma unroll
        for (int k = 0; k < KTRUNC; ++k) {
            int bb = b - k;
            if (bb >= 0) acc = fmaf(Dk[k * RES + t], L[bb * RES + t], acc);
        }
        s_s[t] = acc;
    }
    __syncthreads();
    if (t < PRED) {
        const float* wrow = W_out + t * RES;
        float acc = 0.f;
#pragma unroll
        for (int r = 0; r < RES; ++r) acc = fmaf(s_s[r], wrow[r], acc);
        out[b * PRED + t] = acc;
    }
}

extern "C" void kernel_launch(void* const* d_in, const int* in_sizes, int n_in,
                              void* d_out, int out_size, void* d_ws, size_t ws_size,
                              hipStream_t stream) {
    const float* x     = (const float*)d_in[0];
    const float* W_lin = (const float*)d_in[1];
    const float* W_in  = (const float*)d_in[2];
    const float* d     = (const float*)d_in[3];
    const float* W_out = (const float*)d_in[4];
    float* out = (float*)d_out;
    float* ws  = (float*)d_ws;

    float* M  = ws;
    float* Dk = ws + 2400;
    float* L  = ws + 3200;

    k0_setup<<<1, 256, 0, stream>>>(W_lin, W_in, d, ws);
    k1_local<<<BATCH, 256, 0, stream>>>(x, M, d, L);
    k2_out<<<BATCH, 128, 0, stream>>>(L, Dk, W_out, out);
}